// Round 1
// baseline (212.668 us; speedup 1.0000x reference)
//
#include <hip/hip_runtime.h>

#define NH 128   // hidden
#define NC 384   // edge feature dim
#define NK 32    // neighbors

typedef __attribute__((ext_vector_type(8))) short short8v;   // 8 bf16
typedef __attribute__((ext_vector_type(4))) float f32x4;

#define MFMA16(a, b, c) __builtin_amdgcn_mfma_f32_16x16x32_bf16((a), (b), (c), 0, 0, 0)

__device__ __forceinline__ ushort f2bf(float x) {
  union { float f; unsigned u; } v; v.f = x;
  unsigned r = v.u + 0x7fffu + ((v.u >> 16) & 1u);  // RNE
  return (ushort)(r >> 16);
}

__device__ __forceinline__ short8v ld8(const ushort* p) {
  return *reinterpret_cast<const short8v*>(p);
}
__device__ __forceinline__ void st8(ushort* p, short8v v) {
  *reinterpret_cast<short8v*>(p) = v;
}

// tanh-form GELU (|err| vs exact-erf GELU < 1e-3, far under the 9e-2 tolerance)
__device__ __forceinline__ float gelu_f(float x) {
  float u = 0.7978845608028654f * x * (1.0f + 0.044715f * x * x);
  float uc = fmaxf(u, -20.0f);                 // avoid exp overflow -> NaN
  float e = __expf(-2.0f * uc);
  float t = (1.0f - e) / (1.0f + e);           // tanh(uc)
  return 0.5f * x * (1.0f + t);
}

// ---------------------------------------------------------------------------
// Weight packing: src row-major [k][col] f32 -> bf16 [k/8][col][k%8]
// so a lane's B-fragment (col = lane&15, k = (lane>>4)*8 + j) is one 16B load.
// ushort offsets in ws: W1p 0 (64Ki), W2p 65536 (16Ki), W3p 81920 (16Ki),
// Winp 98304 (64Ki), Woutp 163840 (64Ki).  Total 229376 ushorts = 448 KB.
// ---------------------------------------------------------------------------
__global__ __launch_bounds__(256) void pack_w(
    const float* __restrict__ W1, const float* __restrict__ W2,
    const float* __restrict__ W3, const float* __restrict__ Win,
    const float* __restrict__ Wout, ushort* __restrict__ ws) {
  int id = blockIdx.x * 256 + threadIdx.x;
  if (id < 65536) {                       // W1: K=512, ncol=128
    int t = id, k = t >> 7, c = t & 127;
    ws[(((k >> 3) << 7) + c) * 8 + (k & 7)] = f2bf(W1[t]);
  } else if (id < 81920) {                // W2: K=128, ncol=128
    int t = id - 65536, k = t >> 7, c = t & 127;
    ws[65536 + (((k >> 3) << 7) + c) * 8 + (k & 7)] = f2bf(W2[t]);
  } else if (id < 98304) {                // W3
    int t = id - 81920, k = t >> 7, c = t & 127;
    ws[81920 + (((k >> 3) << 7) + c) * 8 + (k & 7)] = f2bf(W3[t]);
  } else if (id < 163840) {               // Win: K=128, ncol=512
    int t = id - 98304, k = t >> 9, c = t & 511;
    ws[98304 + (((k >> 3) << 9) + c) * 8 + (k & 7)] = f2bf(Win[t]);
  } else {                                // Wout: K=512, ncol=128
    int t = id - 163840, k = t >> 7, c = t & 127;
    ws[163840 + (((k >> 3) << 7) + c) * 8 + (k & 7)] = f2bf(Wout[t]);
  }
}

// ---------------------------------------------------------------------------
// Message kernel: 2 nodes / block, 512 threads (8 waves).
// Wave w owns output columns [w*16, w*16+16) across all 64 edge rows
// -> each weight matrix read exactly once per block (L2-resident).
// LDS: sE 48KB (h_E bf16, XOR-swizzled 16B chunks) + sHV 0.5KB (h_V once per
// node; broadcast A-frags for k<128) + sH1 16KB + sDh/sRed.  sH2 aliases sE.
// ~67KB -> 2 blocks/CU.
// ---------------------------------------------------------------------------
__global__ __launch_bounds__(512, 4) void msg_kernel(
    const float* __restrict__ hV, const float* __restrict__ hE,
    const float* __restrict__ mAtt, const ushort* __restrict__ wsu,
    const float* __restrict__ b1, const float* __restrict__ b2,
    const float* __restrict__ b3, const float* __restrict__ g1,
    const float* __restrict__ be1, float* __restrict__ hmidf,
    ushort* __restrict__ hmidb, int N) {
  const ushort* W1p = wsu;
  const ushort* W2p = wsu + 65536;
  const ushort* W3p = wsu + 81920;

  __shared__ ushort sE[64 * NC];     // 48KB
  __shared__ ushort sHV[2 * NH];     // 512B
  __shared__ ushort sH1[64 * NH];    // 16KB
  __shared__ float  sDh[2 * NH];
  __shared__ float  sRed[16];
  ushort* sH2 = sE;                  // alias: sE dead after layer-1 barrier

  const int tid = threadIdx.x;
  const int w = tid >> 6, lane = tid & 63;
  const int g = lane >> 4, lr = lane & 15;
  const int n0 = blockIdx.x * 2;

  if (tid < 256) sDh[tid] = 0.f;

  // ---- stage h_E -> sE (bf16, swizzled) ----
  {
    const int row = tid >> 3, cb = tid & 7;     // 64 rows x 8 threads
    const int node = row >> 5, e = row & 31;
    const bool valid = (n0 + node) < N;
    const float* src = hE + ((n0 + node) * NK + e) * NC;
#pragma unroll
    for (int j = 0; j < 6; ++j) {
      const int c8 = cb + j * 8;                // 48 chunks of 8 elems per row
      short8v v;
      if (valid) {
        const float4* p = reinterpret_cast<const float4*>(src + c8 * 8);
        float4 f0 = p[0], f1 = p[1];
        v[0] = (short)f2bf(f0.x); v[1] = (short)f2bf(f0.y);
        v[2] = (short)f2bf(f0.z); v[3] = (short)f2bf(f0.w);
        v[4] = (short)f2bf(f1.x); v[5] = (short)f2bf(f1.y);
        v[6] = (short)f2bf(f1.z); v[7] = (short)f2bf(f1.w);
      } else {
#pragma unroll
        for (int q = 0; q < 8; ++q) v[q] = 0;
      }
      st8(sE + row * NC + ((c8 ^ (row & 7)) << 3), v);
    }
  }
  // ---- stage h_V -> sHV (once per node; broadcast rows) ----
  if (tid < 32) {
    const int node = tid >> 4, c8 = tid & 15;
    short8v v;
    if (n0 + node < N) {
      const float4* p = reinterpret_cast<const float4*>(hV + (n0 + node) * NH + c8 * 8);
      float4 f0 = p[0], f1 = p[1];
      v[0] = (short)f2bf(f0.x); v[1] = (short)f2bf(f0.y);
      v[2] = (short)f2bf(f0.z); v[3] = (short)f2bf(f0.w);
      v[4] = (short)f2bf(f1.x); v[5] = (short)f2bf(f1.y);
      v[6] = (short)f2bf(f1.z); v[7] = (short)f2bf(f1.w);
    } else {
#pragma unroll
      for (int q = 0; q < 8; ++q) v[q] = 0;
    }
    st8(sHV + node * NH + c8 * 8, v);
  }
  __syncthreads();

  const int colbase = (w << 4) + lr;   // this lane's output column
  f32x4 acc[4];

  // ================= layer 1: [64,512] @ W1 =================
#pragma unroll
  for (int rt = 0; rt < 4; ++rt) acc[rt] = (f32x4){0.f, 0.f, 0.f, 0.f};
#pragma unroll
  for (int kt = 0; kt < 4; ++kt) {     // k in [0,128): h_V (broadcast rows)
    short8v b = ld8(W1p + ((kt * 4 + g) * 128 + colbase) * 8);
    short8v a0 = ld8(sHV + kt * 32 + g * 8);
    short8v a1 = ld8(sHV + NH + kt * 32 + g * 8);
    acc[0] = MFMA16(a0, b, acc[0]);
    acc[1] = MFMA16(a0, b, acc[1]);
    acc[2] = MFMA16(a1, b, acc[2]);
    acc[3] = MFMA16(a1, b, acc[3]);
  }
#pragma unroll
  for (int kt = 4; kt < 16; ++kt) {    // k in [128,512): h_E from sE
    short8v b = ld8(W1p + ((kt * 4 + g) * 128 + colbase) * 8);
    const int kc = (kt - 4) * 4 + g;
#pragma unroll
    for (int rt = 0; rt < 4; ++rt) {
      const int row = rt * 16 + lr;
      short8v a = ld8(sE + row * NC + ((kc ^ (row & 7)) << 3));
      acc[rt] = MFMA16(a, b, acc[rt]);
    }
  }
  {
    const float bias = b1[colbase];
#pragma unroll
    for (int rt = 0; rt < 4; ++rt) {
#pragma unroll
      for (int i = 0; i < 4; ++i) {
        const int row = rt * 16 + g * 4 + i;
        const float vv = gelu_f(acc[rt][i] + bias);
        sH1[row * NH + ((((colbase >> 3) ^ (row & 7)) << 3) | (colbase & 7))] = f2bf(vv);
      }
    }
  }
  __syncthreads();

  // ================= layer 2: [64,128] @ W2 =================
#pragma unroll
  for (int rt = 0; rt < 4; ++rt) acc[rt] = (f32x4){0.f, 0.f, 0.f, 0.f};
#pragma unroll
  for (int kt = 0; kt < 4; ++kt) {
    short8v b = ld8(W2p + ((kt * 4 + g) * 128 + colbase) * 8);
    const int kc = kt * 4 + g;
#pragma unroll
    for (int rt = 0; rt < 4; ++rt) {
      const int row = rt * 16 + lr;
      short8v a = ld8(sH1 + row * NH + ((kc ^ (row & 7)) << 3));
      acc[rt] = MFMA16(a, b, acc[rt]);
    }
  }
  {
    const float bias = b2[colbase];
#pragma unroll
    for (int rt = 0; rt < 4; ++rt) {
#pragma unroll
      for (int i = 0; i < 4; ++i) {
        const int row = rt * 16 + g * 4 + i;
        const float vv = gelu_f(acc[rt][i] + bias);
        sH2[row * NH + ((((colbase >> 3) ^ (row & 7)) << 3) | (colbase & 7))] = f2bf(vv);
      }
    }
  }
  __syncthreads();

  // ================= layer 3 + masked edge-sum =================
#pragma unroll
  for (int rt = 0; rt < 4; ++rt) acc[rt] = (f32x4){0.f, 0.f, 0.f, 0.f};
#pragma unroll
  for (int kt = 0; kt < 4; ++kt) {
    short8v b = ld8(W3p + ((kt * 4 + g) * 128 + colbase) * 8);
    const int kc = kt * 4 + g;
#pragma unroll
    for (int rt = 0; rt < 4; ++rt) {
      const int row = rt * 16 + lr;
      short8v a = ld8(sH2 + row * NH + ((kc ^ (row & 7)) << 3));
      acc[rt] = MFMA16(a, b, acc[rt]);
    }
  }
  {
    const float bias = b3[colbase];
    float ns0 = 0.f, ns1 = 0.f;
#pragma unroll
    for (int rt = 0; rt < 4; ++rt) {
      const int node = rt >> 1;
      float s = 0.f;
#pragma unroll
      for (int i = 0; i < 4; ++i) {
        const int e = (rt & 1) * 16 + g * 4 + i;
        const float m = (n0 + node < N) ? mAtt[(n0 + node) * NK + e] : 0.f;
        s += (acc[rt][i] + bias) * m;
      }
      s += __shfl_xor(s, 16, 64);
      s += __shfl_xor(s, 32, 64);
      if (rt < 2) ns0 += s; else ns1 += s;
    }
    if (g == 0) { sDh[colbase] = ns0; sDh[NH + colbase] = ns1; }
  }
  __syncthreads();

  // ================= LN1 + write h_mid (f32 + bf16) =================
  if (tid < 256) {
    const int node = tid >> 7, i = tid & 127;
    const int gn = n0 + node;
    float x = 0.f;
    if (gn < N) x = hV[gn * NH + i] + sDh[node * NH + i] * (1.f / 30.f);
    float s = x, q = x * x;
#pragma unroll
    for (int d = 1; d < 64; d <<= 1) {
      s += __shfl_xor(s, d, 64);
      q += __shfl_xor(q, d, 64);
    }
    if (lane == 0) { sRed[w * 2] = s; sRed[w * 2 + 1] = q; }
  }
  __syncthreads();
  if (tid < 256) {
    const int node = tid >> 7, i = tid & 127;
    const int gn = n0 + node;
    if (gn < N) {
      const int wb = node * 2;
      const float s = sRed[wb * 2] + sRed[wb * 2 + 2];
      const float q = sRed[wb * 2 + 1] + sRed[wb * 2 + 3];
      const float mean = s * (1.f / 128.f);
      const float var = q * (1.f / 128.f) - mean * mean;
      const float x = hV[gn * NH + i] + sDh[node * NH + i] * (1.f / 30.f);
      const float y = (x - mean) * rsqrtf(var + 1e-5f) * g1[i] + be1[i];
      hmidf[gn * NH + i] = y;
      hmidb[gn * NH + i] = f2bf(y);
    }
  }
}

// ---------------------------------------------------------------------------
// FFN kernel: 32 nodes / block, 256 threads (4 waves).
// gelu(X @ Win) @ Wout + bias + residual -> LN2 -> *mask_V -> out (f32)
// ---------------------------------------------------------------------------
__global__ __launch_bounds__(256, 2) void ffn_kernel(
    const ushort* __restrict__ wsu, const float* __restrict__ binf,
    const float* __restrict__ boutf, const float* __restrict__ g2,
    const float* __restrict__ be2, const float* __restrict__ maskV,
    const float* __restrict__ hmidf, const ushort* __restrict__ hmidb,
    float* __restrict__ out, int N) {
  const ushort* Winp = wsu + 98304;
  const ushort* Woutp = wsu + 163840;

  __shared__ ushort sX[32 * NH];      // 8KB
  __shared__ ushort sHf[32 * 512];    // 32KB
  __shared__ float  sY[32 * 129];     // 16.5KB (+1 pad vs bank conflicts)

  const int tid = threadIdx.x;
  const int w = tid >> 6, lane = tid & 63;
  const int g = lane >> 4, lr = lane & 15;
  const int n0 = blockIdx.x * 32;

  // stage h_mid (bf16) -> sX swizzled
#pragma unroll
  for (int it = 0; it < 2; ++it) {
    const int cid = tid + it * 256;           // 512 chunks
    const int row = cid >> 4, c8 = cid & 15;
    const int n = n0 + row;
    short8v v;
    if (n < N) v = ld8(hmidb + n * NH + c8 * 8);
    else {
#pragma unroll
      for (int q = 0; q < 8; ++q) v[q] = 0;
    }
    st8(sX + row * NH + ((c8 ^ (row & 7)) << 3), v);
  }
  __syncthreads();

  // -------- layer in: [32,128] @ Win -> gelu -> sHf [32,512] --------
#pragma unroll
  for (int ct8 = 0; ct8 < 8; ++ct8) {
    const int col = (w * 8 + ct8) * 16 + lr;
    f32x4 a0acc = (f32x4){0.f, 0.f, 0.f, 0.f};
    f32x4 a1acc = (f32x4){0.f, 0.f, 0.f, 0.f};
#pragma unroll
    for (int kt = 0; kt < 4; ++kt) {
      short8v b = ld8(Winp + ((kt * 4 + g) * 512 + col) * 8);
      const int kc = kt * 4 + g;
      const int r0 = lr, r1 = 16 + lr;
      short8v a0 = ld8(sX + r0 * NH + ((kc ^ (r0 & 7)) << 3));
      short8v a1 = ld8(sX + r1 * NH + ((kc ^ (r1 & 7)) << 3));
      a0acc = MFMA16(a0, b, a0acc);
      a1acc = MFMA16(a1, b, a1acc);
    }
    const float bi = binf[col];
#pragma unroll
    for (int i = 0; i < 4; ++i) {
      const int row0 = g * 4 + i;
      const int row1 = 16 + g * 4 + i;
      const float v0 = gelu_f(a0acc[i] + bi);
      const float v1 = gelu_f(a1acc[i] + bi);
      sHf[row0 * 512 + ((((col >> 3) ^ (row0 & 7)) << 3) | (col & 7))] = f2bf(v0);
      sHf[row1 * 512 + ((((col >> 3) ^ (row1 & 7)) << 3) | (col & 7))] = f2bf(v1);
    }
  }
  __syncthreads();

  // -------- layer out: [32,512] @ Wout --------
  f32x4 o00 = (f32x4){0.f,0.f,0.f,0.f}, o01 = o00, o10 = o00, o11 = o00;
#pragma unroll
  for (int kt = 0; kt < 16; ++kt) {
    const int kc = kt * 4 + g;
    const int c0 = (2 * w) * 16 + lr, c1 = (2 * w + 1) * 16 + lr;
    short8v b0 = ld8(Woutp + ((kt * 4 + g) * 128 + c0) * 8);
    short8v b1 = ld8(Woutp + ((kt * 4 + g) * 128 + c1) * 8);
    const int r0 = lr, r1 = 16 + lr;
    short8v a0 = ld8(sHf + r0 * 512 + ((kc ^ (r0 & 7)) << 3));
    short8v a1 = ld8(sHf + r1 * 512 + ((kc ^ (r1 & 7)) << 3));
    o00 = MFMA16(a0, b0, o00);
    o01 = MFMA16(a1, b0, o01);
    o10 = MFMA16(a0, b1, o10);
    o11 = MFMA16(a1, b1, o11);
  }
  // epilogue: + bias + residual -> sY
#pragma unroll
  for (int ct = 0; ct < 2; ++ct) {
    const int col = (2 * w + ct) * 16 + lr;
    const float bo = boutf[col];
#pragma unroll
    for (int rt = 0; rt < 2; ++rt) {
      const f32x4 oo = ct == 0 ? (rt == 0 ? o00 : o01) : (rt == 0 ? o10 : o11);
#pragma unroll
      for (int i = 0; i < 4; ++i) {
        const int row = rt * 16 + g * 4 + i;
        const int n = n0 + row;
        const float resid = (n < N) ? hmidf[n * NH + col] : 0.f;
        sY[row * 129 + col] = oo[i] + bo + resid;
      }
    }
  }
  __syncthreads();

  // -------- LN2 + mask + store --------
  {
    const int row = tid >> 3, qq = tid & 7;    // 8 threads per row, 16 cols each
    const int n = n0 + row;
    float vals[16];
    float s = 0.f, q = 0.f;
    const float* yr = sY + row * 129 + qq * 16;
#pragma unroll
    for (int j = 0; j < 16; ++j) { float x = yr[j]; vals[j] = x; s += x; q += x * x; }
    s += __shfl_xor(s, 1, 64);  q += __shfl_xor(q, 1, 64);
    s += __shfl_xor(s, 2, 64);  q += __shfl_xor(q, 2, 64);
    s += __shfl_xor(s, 4, 64);  q += __shfl_xor(q, 4, 64);
    const float mean = s * (1.f / 128.f);
    const float var = q * (1.f / 128.f) - mean * mean;
    const float rs = rsqrtf(var + 1e-5f);
    if (n < N) {
      const float mv = maskV[n];
#pragma unroll
      for (int j = 0; j < 16; ++j) {
        const int col = qq * 16 + j;
        out[n * NH + col] = ((vals[j] - mean) * rs * g2[col] + be2[col]) * mv;
      }
    }
  }
}

extern "C" void kernel_launch(void* const* d_in, const int* in_sizes, int n_in,
                              void* d_out, int out_size, void* d_ws, size_t ws_size,
                              hipStream_t stream) {
  const float* hV   = (const float*)d_in[0];
  const float* hE   = (const float*)d_in[1];
  const float* mV   = (const float*)d_in[2];
  const float* mAtt = (const float*)d_in[3];
  const float* W1   = (const float*)d_in[4];
  const float* b1   = (const float*)d_in[5];
  const float* W2   = (const float*)d_in[6];
  const float* b2   = (const float*)d_in[7];
  const float* W3   = (const float*)d_in[8];
  const float* b3   = (const float*)d_in[9];
  const float* g1   = (const float*)d_in[10];
  const float* be1  = (const float*)d_in[11];
  const float* Win  = (const float*)d_in[12];
  const float* binf = (const float*)d_in[13];
  const float* Wout = (const float*)d_in[14];
  const float* bout = (const float*)d_in[15];
  const float* g2   = (const float*)d_in[16];
  const float* be2  = (const float*)d_in[17];

  const int N = in_sizes[0] / NH;

  ushort* wsu = (ushort*)d_ws;                         // packed weights: 458752 B
  float*  hmidf = (float*)((char*)d_ws + 458752);      // N*128 f32
  ushort* hmidb = (ushort*)((char*)d_ws + 458752 + (size_t)N * NH * 4);  // N*128 bf16
  float*  outp = (float*)d_out;

  pack_w<<<896, 256, 0, stream>>>(W1, W2, W3, Win, Wout, wsu);
  msg_kernel<<<(N + 1) / 2, 512, 0, stream>>>(hV, hE, mAtt, wsu, b1, b2, b3,
                                              g1, be1, hmidf, hmidb, N);
  ffn_kernel<<<(N + 31) / 32, 256, 0, stream>>>(wsu, binf, bout, g2, be2, mV,
                                                hmidf, hmidb, outp, N);
  (void)n_in; (void)out_size; (void)ws_size;
}

// Round 2
// 182.955 us; speedup vs baseline: 1.1624x; 1.1624x over previous
//
#include <hip/hip_runtime.h>
#include <hip/hip_bf16.h>

#define NH 128   // hidden
#define NC 384   // edge feature dim
#define NK 32    // neighbors

typedef __attribute__((ext_vector_type(8))) short short8v;   // 8 bf16
typedef __attribute__((ext_vector_type(4))) float f32x4;

#define MFMA16(a, b, c) __builtin_amdgcn_mfma_f32_16x16x32_bf16((a), (b), (c), 0, 0, 0)

__device__ __forceinline__ ushort f2bf(float x) {
  __hip_bfloat16 h = __float2bfloat16(x);   // compiler emits v_cvt_pk_bf16_f32 pairs
  ushort u;
  __builtin_memcpy(&u, &h, 2);
  return u;
}

__device__ __forceinline__ short8v ld8(const ushort* p) {
  return *reinterpret_cast<const short8v*>(p);
}
__device__ __forceinline__ void st8(ushort* p, short8v v) {
  *reinterpret_cast<short8v*>(p) = v;
}

__device__ __forceinline__ short8v pack8(float4 a, float4 b) {
  short8v v;
  v[0] = (short)f2bf(a.x); v[1] = (short)f2bf(a.y);
  v[2] = (short)f2bf(a.z); v[3] = (short)f2bf(a.w);
  v[4] = (short)f2bf(b.x); v[5] = (short)f2bf(b.y);
  v[6] = (short)f2bf(b.z); v[7] = (short)f2bf(b.w);
  return v;
}

// gelu(x) = x * sigmoid(2u), 2u = x*(1.59576912 + 0.07135481 x^2)
// saturates gracefully: x<<0 -> e=inf -> rcp(inf)=0 -> 0; x>>0 -> e=0 -> x.
__device__ __forceinline__ float gelu_f(float x) {
  float x2 = x * x;
  float m = __builtin_fmaf(0.07135481283f, x2, 1.595769122f);
  float e = __expf(-x * m);
  return x * __builtin_amdgcn_rcpf(1.0f + e);
}

// ---------------------------------------------------------------------------
// Weight packing: src row-major [k][col] f32 -> bf16 [k/8][col][k%8]
// ushort offsets in ws: W1p 0 (64Ki), W2p 65536 (16Ki), W3p 81920 (16Ki),
// Winp 98304 (64Ki), Woutp 163840 (64Ki).  Total 229376 ushorts = 448 KB.
// ---------------------------------------------------------------------------
__global__ __launch_bounds__(256) void pack_w(
    const float* __restrict__ W1, const float* __restrict__ W2,
    const float* __restrict__ W3, const float* __restrict__ Win,
    const float* __restrict__ Wout, ushort* __restrict__ ws) {
  int id = blockIdx.x * 256 + threadIdx.x;
  if (id < 65536) {                       // W1: K=512, ncol=128
    int t = id, k = t >> 7, c = t & 127;
    ws[(((k >> 3) << 7) + c) * 8 + (k & 7)] = f2bf(W1[t]);
  } else if (id < 81920) {                // W2: K=128, ncol=128
    int t = id - 65536, k = t >> 7, c = t & 127;
    ws[65536 + (((k >> 3) << 7) + c) * 8 + (k & 7)] = f2bf(W2[t]);
  } else if (id < 98304) {                // W3
    int t = id - 81920, k = t >> 7, c = t & 127;
    ws[81920 + (((k >> 3) << 7) + c) * 8 + (k & 7)] = f2bf(W3[t]);
  } else if (id < 163840) {               // Win: K=128, ncol=512
    int t = id - 98304, k = t >> 9, c = t & 511;
    ws[98304 + (((k >> 3) << 9) + c) * 8 + (k & 7)] = f2bf(Win[t]);
  } else {                                // Wout: K=512, ncol=128
    int t = id - 163840, k = t >> 7, c = t & 127;
    ws[163840 + (((k >> 3) << 7) + c) * 8 + (k & 7)] = f2bf(Wout[t]);
  }
}

// ---------------------------------------------------------------------------
// Message kernel: 2 nodes / block, 512 threads (8 waves).
// All 12 global loads (whole 98KB h_E slab) issued up front; converted and
// consumed chunk-by-chunk (3 x 128-k chunks) through a 2 x 16KB double
// buffer, so MFMA of chunk c overlaps HBM arrival of chunks c+1..2.
// LDS: sEb 32KB + sH1 16KB + sHV/sDh/sRed ~1.6KB.  sH2 aliases sEb[0].
// ---------------------------------------------------------------------------
__global__ __launch_bounds__(512, 4) void msg_kernel(
    const float* __restrict__ hV, const float* __restrict__ hE,
    const float* __restrict__ mAtt, const ushort* __restrict__ wsu,
    const float* __restrict__ b1, const float* __restrict__ b2,
    const float* __restrict__ b3, const float* __restrict__ g1,
    const float* __restrict__ be1, float* __restrict__ hmidf,
    ushort* __restrict__ hmidb, int N) {
  const ushort* W1p = wsu;
  const ushort* W2p = wsu + 65536;
  const ushort* W3p = wsu + 81920;

  __shared__ ushort sEb[2][64 * 128];  // 2 x 16KB chunk buffers
  __shared__ ushort sHV[2 * NH];       // 512B
  __shared__ ushort sH1[64 * 128];     // 16KB
  __shared__ float  sDh[2 * NH];
  __shared__ float  sRed[16];
  ushort* sH2 = sEb[0];                // alias: sEb dead after layer-1

  const int tid = threadIdx.x;
  const int w = tid >> 6, lane = tid & 63;
  const int g = lane >> 4, lr = lane & 15;
  const int n0 = blockIdx.x * 2;

  // ---- issue ALL h_E loads up front (12 x 16B per thread) ----
  const int row = tid >> 3, cb = tid & 7;      // 64 rows x 8 threads
  const int node = row >> 5, e = row & 31;
  const bool valid = (n0 + node) < N;
  const float* src = hE + (valid ? ((size_t)(n0 + node) * NK + e) * NC : 0);
  float4 L[3][2][2];
#pragma unroll
  for (int q = 0; q < 3; ++q)
#pragma unroll
    for (int h = 0; h < 2; ++h) {
      const float4* p = reinterpret_cast<const float4*>(src + q * 128 + h * 64 + cb * 8);
      L[q][h][0] = p[0];
      L[q][h][1] = p[1];
    }

  // ---- stage h_V (broadcast rows) ----
  if (tid < 32) {
    const int nd = tid >> 4, c8 = tid & 15;
    short8v v = {0, 0, 0, 0, 0, 0, 0, 0};
    if (n0 + nd < N) {
      const float4* p = reinterpret_cast<const float4*>(hV + (size_t)(n0 + nd) * NH + c8 * 8);
      v = pack8(p[0], p[1]);
    }
    st8(sHV + nd * NH + c8 * 8, v);
  }

  const int rsw = row & 15;
  // ---- convert + write chunk 0 -> sEb[0] ----
#pragma unroll
  for (int h = 0; h < 2; ++h) {
    short8v v = valid ? pack8(L[0][h][0], L[0][h][1]) : (short8v){0, 0, 0, 0, 0, 0, 0, 0};
    st8(&sEb[0][row * 128 + (((cb + 8 * h) ^ rsw) << 3)], v);
  }
  __syncthreads();

  const int colbase = (w << 4) + lr;   // this lane's output column
  f32x4 acc[4];
#pragma unroll
  for (int rt = 0; rt < 4; ++rt) acc[rt] = (f32x4){0.f, 0.f, 0.f, 0.f};

  // ===== layer 1, phase 0: h_V part (kt 0..3) + chunk0 (kt 4..7) =====
#pragma unroll
  for (int kt = 0; kt < 4; ++kt) {
    short8v b = ld8(W1p + ((kt * 4 + g) * 128 + colbase) * 8);
    short8v a0 = ld8(sHV + kt * 32 + g * 8);
    short8v a1 = ld8(sHV + NH + kt * 32 + g * 8);
    acc[0] = MFMA16(a0, b, acc[0]);
    acc[1] = MFMA16(a0, b, acc[1]);
    acc[2] = MFMA16(a1, b, acc[2]);
    acc[3] = MFMA16(a1, b, acc[3]);
  }
#pragma unroll
  for (int j = 0; j < 4; ++j) {        // chunk 0
    short8v b = ld8(W1p + (((4 + j) * 4 + g) * 128 + colbase) * 8);
    const int kcg = j * 4 + g;
#pragma unroll
    for (int rt = 0; rt < 4; ++rt) {
      const int r2 = rt * 16 + lr;
      short8v a = ld8(&sEb[0][r2 * 128 + ((kcg ^ (r2 & 15)) << 3)]);
      acc[rt] = MFMA16(a, b, acc[rt]);
    }
  }
  // write chunk 1 -> sEb[1]
#pragma unroll
  for (int h = 0; h < 2; ++h) {
    short8v v = valid ? pack8(L[1][h][0], L[1][h][1]) : (short8v){0, 0, 0, 0, 0, 0, 0, 0};
    st8(&sEb[1][row * 128 + (((cb + 8 * h) ^ rsw) << 3)], v);
  }
  __syncthreads();

  // ===== phase 1: chunk1 (kt 8..11); write chunk2 -> sEb[0] =====
#pragma unroll
  for (int j = 0; j < 4; ++j) {
    short8v b = ld8(W1p + (((8 + j) * 4 + g) * 128 + colbase) * 8);
    const int kcg = j * 4 + g;
#pragma unroll
    for (int rt = 0; rt < 4; ++rt) {
      const int r2 = rt * 16 + lr;
      short8v a = ld8(&sEb[1][r2 * 128 + ((kcg ^ (r2 & 15)) << 3)]);
      acc[rt] = MFMA16(a, b, acc[rt]);
    }
  }
#pragma unroll
  for (int h = 0; h < 2; ++h) {
    short8v v = valid ? pack8(L[2][h][0], L[2][h][1]) : (short8v){0, 0, 0, 0, 0, 0, 0, 0};
    st8(&sEb[0][row * 128 + (((cb + 8 * h) ^ rsw) << 3)], v);
  }
  __syncthreads();

  // ===== phase 2: chunk2 (kt 12..15) =====
#pragma unroll
  for (int j = 0; j < 4; ++j) {
    short8v b = ld8(W1p + (((12 + j) * 4 + g) * 128 + colbase) * 8);
    const int kcg = j * 4 + g;
#pragma unroll
    for (int rt = 0; rt < 4; ++rt) {
      const int r2 = rt * 16 + lr;
      short8v a = ld8(&sEb[0][r2 * 128 + ((kcg ^ (r2 & 15)) << 3)]);
      acc[rt] = MFMA16(a, b, acc[rt]);
    }
  }
  // layer-1 epilogue: bias + gelu -> sH1
  {
    const float bias = b1[colbase];
#pragma unroll
    for (int rt = 0; rt < 4; ++rt) {
#pragma unroll
      for (int i = 0; i < 4; ++i) {
        const int rr = rt * 16 + g * 4 + i;
        const float vv = gelu_f(acc[rt][i] + bias);
        sH1[rr * 128 + ((((colbase >> 3) ^ (rr & 15)) << 3) | (colbase & 7))] = f2bf(vv);
      }
    }
  }
  __syncthreads();

  // ================= layer 2: [64,128] @ W2 =================
#pragma unroll
  for (int rt = 0; rt < 4; ++rt) acc[rt] = (f32x4){0.f, 0.f, 0.f, 0.f};
#pragma unroll
  for (int kt = 0; kt < 4; ++kt) {
    short8v b = ld8(W2p + ((kt * 4 + g) * 128 + colbase) * 8);
    const int kcg = kt * 4 + g;
#pragma unroll
    for (int rt = 0; rt < 4; ++rt) {
      const int r2 = rt * 16 + lr;
      short8v a = ld8(&sH1[r2 * 128 + ((kcg ^ (r2 & 15)) << 3)]);
      acc[rt] = MFMA16(a, b, acc[rt]);
    }
  }
  {
    const float bias = b2[colbase];
#pragma unroll
    for (int rt = 0; rt < 4; ++rt) {
#pragma unroll
      for (int i = 0; i < 4; ++i) {
        const int rr = rt * 16 + g * 4 + i;
        const float vv = gelu_f(acc[rt][i] + bias);
        sH2[rr * 128 + ((((colbase >> 3) ^ (rr & 15)) << 3) | (colbase & 7))] = f2bf(vv);
      }
    }
  }
  __syncthreads();

  // ================= layer 3 + masked edge-sum =================
#pragma unroll
  for (int rt = 0; rt < 4; ++rt) acc[rt] = (f32x4){0.f, 0.f, 0.f, 0.f};
#pragma unroll
  for (int kt = 0; kt < 4; ++kt) {
    short8v b = ld8(W3p + ((kt * 4 + g) * 128 + colbase) * 8);
    const int kcg = kt * 4 + g;
#pragma unroll
    for (int rt = 0; rt < 4; ++rt) {
      const int r2 = rt * 16 + lr;
      short8v a = ld8(&sH2[r2 * 128 + ((kcg ^ (r2 & 15)) << 3)]);
      acc[rt] = MFMA16(a, b, acc[rt]);
    }
  }
  {
    const float bias = b3[colbase];
    float ns0 = 0.f, ns1 = 0.f;
#pragma unroll
    for (int rt = 0; rt < 4; ++rt) {
      const int nd = rt >> 1;
      float s = 0.f;
#pragma unroll
      for (int i = 0; i < 4; ++i) {
        const int e2 = (rt & 1) * 16 + g * 4 + i;
        const float m = (n0 + nd < N) ? mAtt[(size_t)(n0 + nd) * NK + e2] : 0.f;
        s += (acc[rt][i] + bias) * m;
      }
      s += __shfl_xor(s, 16, 64);
      s += __shfl_xor(s, 32, 64);
      if (rt < 2) ns0 += s; else ns1 += s;
    }
    if (g == 0) { sDh[colbase] = ns0; sDh[NH + colbase] = ns1; }
  }
  __syncthreads();

  // ================= LN1 + write h_mid (f32 + bf16) =================
  float x_ln = 0.f;
  if (tid < 256) {
    const int nd = tid >> 7, i = tid & 127;
    const int gn = n0 + nd;
    if (gn < N) x_ln = hV[(size_t)gn * NH + i] + sDh[nd * NH + i] * (1.f / 30.f);
    float s = x_ln, qv = x_ln * x_ln;
#pragma unroll
    for (int d = 1; d < 64; d <<= 1) {
      s += __shfl_xor(s, d, 64);
      qv += __shfl_xor(qv, d, 64);
    }
    if (lane == 0) { sRed[w * 2] = s; sRed[w * 2 + 1] = qv; }
  }
  __syncthreads();
  if (tid < 256) {
    const int nd = tid >> 7, i = tid & 127;
    const int gn = n0 + nd;
    if (gn < N) {
      const int wb = nd * 2;
      const float s = sRed[wb * 2] + sRed[wb * 2 + 2];
      const float qv = sRed[wb * 2 + 1] + sRed[wb * 2 + 3];
      const float mean = s * (1.f / 128.f);
      const float var = qv * (1.f / 128.f) - mean * mean;
      const float y = (x_ln - mean) * rsqrtf(var + 1e-5f) * g1[i] + be1[i];
      hmidf[(size_t)gn * NH + i] = y;
      hmidb[(size_t)gn * NH + i] = f2bf(y);
    }
  }
}

// ---------------------------------------------------------------------------
// FFN kernel: 16 nodes / block (625 blocks), 256 threads (4 waves).
// gelu(X @ Win) @ Wout + bias + residual -> LN2 -> *mask_V -> out (f32)
// ---------------------------------------------------------------------------
__global__ __launch_bounds__(256, 4) void ffn_kernel(
    const ushort* __restrict__ wsu, const float* __restrict__ binf,
    const float* __restrict__ boutf, const float* __restrict__ g2,
    const float* __restrict__ be2, const float* __restrict__ maskV,
    const float* __restrict__ hmidf, const ushort* __restrict__ hmidb,
    float* __restrict__ out, int N) {
  const ushort* Winp = wsu + 98304;
  const ushort* Woutp = wsu + 163840;

  __shared__ ushort sX[16 * 128];     // 4KB
  __shared__ ushort sHf[16 * 512];    // 16KB
  __shared__ float  sY[16 * 132];     // 8.25KB, pad to 132 (33 words -> +r skew)

  const int tid = threadIdx.x;
  const int w = tid >> 6, lane = tid & 63;
  const int g = lane >> 4, lr = lane & 15;
  const int n0 = blockIdx.x * 16;

  // stage h_mid (bf16) -> sX swizzled (256 chunks, one per thread)
  {
    const int rr = tid >> 4, c8 = tid & 15;
    const int n = n0 + rr;
    short8v v = {0, 0, 0, 0, 0, 0, 0, 0};
    if (n < N) v = ld8(hmidb + (size_t)n * NH + c8 * 8);
    st8(sX + rr * 128 + ((c8 ^ (rr & 15)) << 3), v);
  }
  __syncthreads();

  // -------- layer in: [16,128] @ Win -> gelu -> sHf [16,512] --------
#pragma unroll
  for (int ct8 = 0; ct8 < 8; ++ct8) {
    const int col = (w * 8 + ct8) * 16 + lr;
    f32x4 a0acc = (f32x4){0.f, 0.f, 0.f, 0.f};
#pragma unroll
    for (int kt = 0; kt < 4; ++kt) {
      short8v b = ld8(Winp + ((kt * 4 + g) * 512 + col) * 8);
      const int kcg = kt * 4 + g;
      const int r0 = lr;
      short8v a0 = ld8(sX + r0 * 128 + ((kcg ^ (r0 & 15)) << 3));
      a0acc = MFMA16(a0, b, a0acc);
    }
    const float bi = binf[col];
#pragma unroll
    for (int i = 0; i < 4; ++i) {
      const int rr = g * 4 + i;
      const float v0 = gelu_f(a0acc[i] + bi);
      sHf[rr * 512 + ((((col >> 3) ^ (rr & 15)) << 3) | (col & 7))] = f2bf(v0);
    }
  }
  __syncthreads();

  // -------- layer out: [16,512] @ Wout (wave w -> cols [w*32, w*32+32)) -----
  f32x4 o0 = (f32x4){0.f, 0.f, 0.f, 0.f}, o1 = o0;
#pragma unroll
  for (int kt = 0; kt < 16; ++kt) {
    const int kcg = kt * 4 + g;                 // [0,64)
    const int c0 = (2 * w) * 16 + lr, c1 = (2 * w + 1) * 16 + lr;
    short8v b0 = ld8(Woutp + (kcg * 128 + c0) * 8);
    short8v b1 = ld8(Woutp + (kcg * 128 + c1) * 8);
    const int r0 = lr;
    short8v a0 = ld8(sHf + r0 * 512 + ((kcg ^ (r0 & 15)) << 3));
    o0 = MFMA16(a0, b0, o0);
    o1 = MFMA16(a0, b1, o1);
  }
  // epilogue: + bias + residual -> sY
#pragma unroll
  for (int ct = 0; ct < 2; ++ct) {
    const int col = (2 * w + ct) * 16 + lr;
    const float bo = boutf[col];
    const f32x4 oo = ct ? o1 : o0;
#pragma unroll
    for (int i = 0; i < 4; ++i) {
      const int rr = g * 4 + i;
      const int n = n0 + rr;
      const float resid = (n < N) ? hmidf[(size_t)n * NH + col] : 0.f;
      sY[rr * 132 + col] = oo[i] + bo + resid;
    }
  }
  __syncthreads();

  // -------- LN2 + mask + store (16 threads per row, 8 cols each) --------
  {
    const int rr = tid >> 4, qq = tid & 15;
    const int n = n0 + rr;
    float vals[8];
    float s = 0.f, qs = 0.f;
    const float* yr = sY + rr * 132 + qq * 8;
#pragma unroll
    for (int j = 0; j < 8; ++j) { float x = yr[j]; vals[j] = x; s += x; qs += x * x; }
    s += __shfl_xor(s, 1, 64);  qs += __shfl_xor(qs, 1, 64);
    s += __shfl_xor(s, 2, 64);  qs += __shfl_xor(qs, 2, 64);
    s += __shfl_xor(s, 4, 64);  qs += __shfl_xor(qs, 4, 64);
    s += __shfl_xor(s, 8, 64);  qs += __shfl_xor(qs, 8, 64);
    const float mean = s * (1.f / 128.f);
    const float var = qs * (1.f / 128.f) - mean * mean;
    const float rs = rsqrtf(var + 1e-5f);
    if (n < N) {
      const float mv = maskV[n];
#pragma unroll
      for (int j = 0; j < 8; ++j) {
        const int col = qq * 8 + j;
        out[(size_t)n * NH + col] = ((vals[j] - mean) * rs * g2[col] + be2[col]) * mv;
      }
    }
  }
}

extern "C" void kernel_launch(void* const* d_in, const int* in_sizes, int n_in,
                              void* d_out, int out_size, void* d_ws, size_t ws_size,
                              hipStream_t stream) {
  const float* hV   = (const float*)d_in[0];
  const float* hE   = (const float*)d_in[1];
  const float* mV   = (const float*)d_in[2];
  const float* mAtt = (const float*)d_in[3];
  const float* W1   = (const float*)d_in[4];
  const float* b1   = (const float*)d_in[5];
  const float* W2   = (const float*)d_in[6];
  const float* b2   = (const float*)d_in[7];
  const float* W3   = (const float*)d_in[8];
  const float* b3   = (const float*)d_in[9];
  const float* g1   = (const float*)d_in[10];
  const float* be1  = (const float*)d_in[11];
  const float* Win  = (const float*)d_in[12];
  const float* binf = (const float*)d_in[13];
  const float* Wout = (const float*)d_in[14];
  const float* bout = (const float*)d_in[15];
  const float* g2   = (const float*)d_in[16];
  const float* be2  = (const float*)d_in[17];

  const int N = in_sizes[0] / NH;

  ushort* wsu = (ushort*)d_ws;                         // packed weights: 458752 B
  float*  hmidf = (float*)((char*)d_ws + 458752);      // N*128 f32
  ushort* hmidb = (ushort*)((char*)d_ws + 458752 + (size_t)N * NH * 4);  // N*128 bf16
  float*  outp = (float*)d_out;

  pack_w<<<896, 256, 0, stream>>>(W1, W2, W3, Win, Wout, wsu);
  msg_kernel<<<(N + 1) / 2, 512, 0, stream>>>(hV, hE, mAtt, wsu, b1, b2, b3,
                                              g1, be1, hmidf, hmidb, N);
  ffn_kernel<<<(N + 15) / 16, 256, 0, stream>>>(wsu, binf, bout, g2, be2, mV,
                                                hmidf, hmidb, outp, N);
  (void)n_in; (void)out_size; (void)ws_size;
}